// Round 4
// baseline (1091.731 us; speedup 1.0000x reference)
//
#include <hip/hip_runtime.h>
#include <hip/hip_bf16.h>

// ---------------------------------------------------------------------------
// MLDecoder forward on MI355X (gfx950).  Round 4:
//  - NEW fused attention kernel (QK^T -> in-register softmax -> PV) replacing
//    the scores/softmax/ctx GEMM chains for BOTH self- and cross-attention.
//    Kills ~200 MB of f32/bf16 score-matrix intermediate traffic.
//  - Everything else retained from round 3 (batch-invariant self-attn &
//    cross-query path, combined cross weights, split-K + fused reduce/LN,
//    global_load_lds GEMM staging, XCD swizzle).
// ---------------------------------------------------------------------------

typedef __attribute__((ext_vector_type(8))) short short8;   // 8 bf16
typedef __attribute__((ext_vector_type(4))) short short4b;  // 4 bf16
typedef __attribute__((ext_vector_type(4))) float floatx4;

#define DEVI static __device__ __forceinline__

DEVI short f2bf(float f) {
    union { __hip_bfloat16 h; short s; } u;
    u.h = __float2bfloat16(f);
    return u.s;
}

DEVI void gld_lds16(const void* g, void* l) {
    __builtin_amdgcn_global_load_lds(
        (const __attribute__((address_space(1))) void*)g,
        (__attribute__((address_space(3))) void*)l, 16, 0, 0);
}

// ---------------------------------------------------------------------------
// Tiled GEMM:  C[m,n] = act(alpha * sum_k A[m,k]*B[k,n] + bias[n]) + resid
//   A bf16 row-major [M,K] (lda), B bf16 BT layout [N,K] (ldb).
// Mpad/Npad: staging bounds; C-write masked by true M,N.  K % 64 == 0.
// Batched via blockIdx.z (outer/inner); split-K via the same machinery.
// ---------------------------------------------------------------------------
template<int ACT, bool OUT_BF16>
__global__ __launch_bounds__(256)
void gemm_kernel(const short* __restrict__ Ap, const short* __restrict__ Bp,
                 const float* __restrict__ bias, const float* __restrict__ resid,
                 void* __restrict__ Cp,
                 int M, int N, int K, int Mpad, int Npad,
                 int lda, int ldb, int ldc, int inner_batch,
                 long sA1, long sA2, long sB1, long sB2, long sC1, long sC2,
                 float alpha)
{
    constexpr int BM = 128, BN = 128, BK = 64;
    __shared__ __align__(16) short As[BM][BK];
    __shared__ __align__(16) short Bs[BN][BK];

    // ---- XCD-chunked bijective block swizzle (m204) ----
    const int gx = gridDim.x, gy = gridDim.y;
    const long nwg = (long)gx * gy * gridDim.z;
    const long dfl = blockIdx.x + (long)gx * (blockIdx.y + (long)gy * blockIdx.z);
    const long qch = nwg >> 3, rch = nwg & 7;
    const long xcd = dfl & 7, idx = dfl >> 3;
    const long w = (xcd < rch ? xcd * (qch + 1) : rch * (qch + 1) + (xcd - rch) * qch) + idx;
    const int bx = (int)(w % gx);
    const long wt = w / gx;
    const int by = (int)(wt % gy);
    const int bz = (int)(wt / gy);

    const int outer = bz / inner_batch;
    const int inner = bz - outer * inner_batch;
    const long aoff = (long)outer * sA1 + (long)inner * sA2;
    const long boff = (long)outer * sB1 + (long)inner * sB2;
    const long coff = (long)outer * sC1 + (long)inner * sC2;
    const int m0 = by * BM, n0 = bx * BN;
    const int tid = threadIdx.x;
    const int wid = tid >> 6, lane = tid & 63;
    const int wm = (wid >> 1) << 6, wn = (wid & 1) << 6;  // 2x2 waves, 64x64 each
    const int fr = lane & 15;
    const int fk = (lane >> 4) << 3;

    const short* A = Ap + aoff;
    const short* B = Bp + boff;
    const int rowp = tid >> 3;                // 0..31
    const int col8 = (tid & 7) << 3;          // 0..56
    const int wrow = (tid >> 6) << 3;         // wave id * 8

    floatx4 acc[4][4] = {};

    for (int kt = 0; kt < K; kt += BK) {
        const bool fastA = (m0 + BM <= Mpad) && (kt + BK <= K);
        const bool fastB = (n0 + BN <= Npad) && (kt + BK <= K);

        if (fastA) {
            const short* src = A + (long)(m0 + rowp) * lda + kt + col8;
            const long rstride = (long)lda << 5;   // 32 rows
            #pragma unroll
            for (int p = 0; p < 4; ++p)
                gld_lds16(src + p * rstride, &As[(p << 5) + wrow][0]);
        } else {
            #pragma unroll
            for (int i = 0; i < 4; ++i) {
                const int row = rowp + (i << 5);
                const int gm = m0 + row, gk = kt + col8;
                short8 v;
                if (gm < M && gk + 8 <= K) {
                    v = *(const short8*)(A + (long)gm * lda + gk);
                } else {
                    #pragma unroll
                    for (int j = 0; j < 8; ++j)
                        v[j] = (gm < M && gk + j < K) ? A[(long)gm * lda + gk + j] : (short)0;
                }
                *(short8*)(&As[row][col8]) = v;
            }
        }
        if (fastB) {
            const short* src = B + (long)(n0 + rowp) * ldb + kt + col8;
            const long rstride = (long)ldb << 5;
            #pragma unroll
            for (int p = 0; p < 4; ++p)
                gld_lds16(src + p * rstride, &Bs[(p << 5) + wrow][0]);
        } else {
            #pragma unroll
            for (int i = 0; i < 4; ++i) {
                const int row = rowp + (i << 5);
                const int gn = n0 + row, gk = kt + col8;
                short8 v;
                if (gn < N && gk + 8 <= K) {
                    v = *(const short8*)(B + (long)gn * ldb + gk);
                } else {
                    #pragma unroll
                    for (int j = 0; j < 8; ++j)
                        v[j] = (gn < N && gk + j < K) ? B[(long)gn * ldb + gk + j] : (short)0;
                }
                *(short8*)(&Bs[row][col8]) = v;
            }
        }
        __syncthreads();

        #pragma unroll
        for (int kk = 0; kk < BK; kk += 32) {
            short8 af[4], bfv[4];
            #pragma unroll
            for (int i = 0; i < 4; ++i)
                af[i] = *(const short8*)(&As[wm + (i << 4) + fr][kk + fk]);
            #pragma unroll
            for (int j = 0; j < 4; ++j)
                bfv[j] = *(const short8*)(&Bs[wn + (j << 4) + fr][kk + fk]);
            #pragma unroll
            for (int i = 0; i < 4; ++i)
                #pragma unroll
                for (int j = 0; j < 4; ++j)
                    acc[i][j] = __builtin_amdgcn_mfma_f32_16x16x32_bf16(af[i], bfv[j], acc[i][j], 0, 0, 0);
        }
        __syncthreads();
    }

    #pragma unroll
    for (int j = 0; j < 4; ++j) {
        const int col = n0 + wn + (j << 4) + fr;
        if (col >= N) continue;
        const float bv = bias ? bias[col] : 0.0f;
        #pragma unroll
        for (int i = 0; i < 4; ++i) {
            #pragma unroll
            for (int r = 0; r < 4; ++r) {
                const int row = m0 + wm + (i << 4) + ((lane >> 4) << 2) + r;
                if (row >= M) continue;
                float v = acc[i][j][r] * alpha + bv;
                if constexpr (ACT == 1) v = fmaxf(v, 0.0f);
                if constexpr (ACT == 2) {
                    v = 0.5f * v * (1.0f + tanhf(0.7978845608028654f * (v + 0.044715f * v * v * v)));
                }
                const long ci = coff + (long)row * ldc + col;
                if (resid) v += resid[ci];
                if constexpr (OUT_BF16) ((short*)Cp)[ci] = f2bf(v);
                else                    ((float*)Cp)[ci] = v;
            }
        }
    }
}

// ---------------------------------------------------------------------------
// Fused attention: per block = one (b, h).
//   S = scale * Q_h[128 x 768] @ K_b^T   (K_b: [tokens][768+?] rows, ldk)
//   P = softmax_row(S) masked to nt tokens
//   C[q, h*768 + d] = P @ V_b            (V supplied TRANSPOSED: [d][t], ldv)
// NTT: token tiles of 16; padded tokens KP = NTT*16 (14 -> 224 cross,
// 8 -> 128 self).  VT must be ZERO for t in [nt, KP).  Q rows beyond 100 and
// K rows beyond nt may be garbage (finite or NaN bits) - row/col isolated
// and masked.  Output rows q < 100 only.
// ---------------------------------------------------------------------------
template<int NTT>
__global__ __launch_bounds__(256)
void attn_kernel(const short* __restrict__ Qp, const short* __restrict__ Kp,
                 const short* __restrict__ VTp, short* __restrict__ Cp,
                 int nt, int nh,
                 int ldq, int ldk, int ldv, int ldc,
                 int khs, int vhs,
                 long sK, long sVT, long sC,
                 float scale)
{
    constexpr int KP  = NTT * 16;
    constexpr int PLD = KP + 8;      // P leading dim (shorts); row stride 16B-mult
    constexpr int LDS_SHORTS = (128 * PLD > KP * 64) ? 128 * PLD : KP * 64;
    __shared__ __align__(16) short lds[LDS_SHORTS];
    short (*Ks)[64]  = reinterpret_cast<short (*)[64]>(lds);
    short (*Pl)[PLD] = reinterpret_cast<short (*)[PLD]>(lds);

    const int blk = blockIdx.x;
    const int nb = gridDim.x / nh;
    int b, h;
    if (nb == 64) {  // XCD-grouping: all 8 heads of a batch land consecutively
        b = ((blk & 7) << 3) + (blk >> 6);
        h = (blk >> 3) & 7;
    } else {
        b = blk / nh; h = blk - b * nh;
    }

    const int tid = threadIdx.x, wid = tid >> 6, lane = tid & 63;
    const int fr = lane & 15;
    const int g4 = (lane >> 4) << 2;          // C-row sub-offset
    const int fk = (lane >> 4) << 3;          // k offset in shorts

    const short* Qh = Qp + h * 768;
    const short* Kb = Kp + (long)b * sK + h * khs;
    const short* Vb = VTp + (long)b * sVT + (long)h * vhs * ldv;

    // ---------------- Phase A: S = Q K^T ----------------
    const int wmA = wid << 5;                 // 32 rows per wave
    floatx4 accS[2][NTT];
    #pragma unroll
    for (int i = 0; i < 2; ++i)
        #pragma unroll
        for (int j = 0; j < NTT; ++j) accS[i][j] = (floatx4){0.f, 0.f, 0.f, 0.f};

    const int srow = tid >> 3, scol = (tid & 7) << 3;
    const int wrow = (tid >> 6) << 3;

    for (int kt = 0; kt < 768; kt += 64) {
        const short* src0 = Kb + (long)srow * ldk + kt + scol;
        #pragma unroll
        for (int p = 0; p < KP / 32; ++p)
            gld_lds16(src0 + (long)p * 32 * ldk, &Ks[p * 32 + wrow][0]);
        __syncthreads();
        #pragma unroll
        for (int kk = 0; kk < 64; kk += 32) {
            short8 aF[2];
            #pragma unroll
            for (int i = 0; i < 2; ++i)
                aF[i] = *(const short8*)(Qh + (long)(wmA + i * 16 + fr) * ldq + kt + kk + fk);
            #pragma unroll
            for (int j = 0; j < NTT; ++j) {
                const short8 bF = *(const short8*)(&Ks[j * 16 + fr][kk + fk]);
                accS[0][j] = __builtin_amdgcn_mfma_f32_16x16x32_bf16(aF[0], bF, accS[0][j], 0, 0, 0);
                accS[1][j] = __builtin_amdgcn_mfma_f32_16x16x32_bf16(aF[1], bF, accS[1][j], 0, 0, 0);
            }
        }
        __syncthreads();
    }

    // ---------------- softmax (in-register, rows in 16-lane groups) --------
    float inv[2][4];
    #pragma unroll
    for (int i = 0; i < 2; ++i) {
        #pragma unroll
        for (int r = 0; r < 4; ++r) {
            float m = -1e30f;
            #pragma unroll
            for (int j = 0; j < NTT; ++j) {
                const int col = j * 16 + fr;
                if (col < nt) m = fmaxf(m, accS[i][j][r]);
            }
            #pragma unroll
            for (int off = 1; off < 16; off <<= 1) m = fmaxf(m, __shfl_xor(m, off));
            float s = 0.0f;
            #pragma unroll
            for (int j = 0; j < NTT; ++j) {
                const int col = j * 16 + fr;
                float e = (col < nt) ? __expf((accS[i][j][r] - m) * scale) : 0.0f;
                accS[i][j][r] = e;
                s += e;
            }
            #pragma unroll
            for (int off = 1; off < 16; off <<= 1) s += __shfl_xor(s, off);
            inv[i][r] = 1.0f / s;
        }
    }

    // write P (bf16) into LDS [128][PLD]; all KP cols covered (pads are 0)
    #pragma unroll
    for (int i = 0; i < 2; ++i)
        #pragma unroll
        for (int j = 0; j < NTT; ++j)
            #pragma unroll
            for (int r = 0; r < 4; ++r)
                Pl[wmA + i * 16 + g4 + r][j * 16 + fr] = f2bf(accS[i][j][r] * inv[i][r]);
    __syncthreads();

    // ---------------- Phase B: C = P @ V ----------------
    const int wm2 = (wid >> 1) << 6;
    const int wn2 = (wid & 1) << 6;
    short* Cb = Cp + (long)b * sC + h * 768;

    for (int n0 = 0; n0 < 768; n0 += 128) {
        floatx4 acc2[4][4];
        #pragma unroll
        for (int i = 0; i < 4; ++i)
            #pragma unroll
            for (int j = 0; j < 4; ++j) acc2[i][j] = (floatx4){0.f, 0.f, 0.f, 0.f};
        #pragma unroll
        for (int kk = 0; kk < KP; kk += 32) {
            short8 aF[4], bF[4];
            #pragma unroll
            for (int i = 0; i < 4; ++i)
                aF[i] = *(const short8*)(&Pl[wm2 + i * 16 + fr][kk + fk]);
            #pragma unroll
            for (int j = 0; j < 4; ++j)
                bF[j] = *(const short8*)(Vb + (long)(n0 + wn2 + j * 16 + fr) * ldv + kk + fk);
            #pragma unroll
            for (int i = 0; i < 4; ++i)
                #pragma unroll
                for (int j = 0; j < 4; ++j)
                    acc2[i][j] = __builtin_amdgcn_mfma_f32_16x16x32_bf16(aF[i], bF[j], acc2[i][j], 0, 0, 0);
        }
        #pragma unroll
        for (int j = 0; j < 4; ++j) {
            const int col = n0 + wn2 + (j << 4) + fr;
            #pragma unroll
            for (int i = 0; i < 4; ++i) {
                #pragma unroll
                for (int r = 0; r < 4; ++r) {
                    const int row = wm2 + (i << 4) + g4 + r;
                    if (row < 100)
                        Cb[(long)row * ldc + col] = f2bf(acc2[i][j][r]);
                }
            }
        }
    }
}

// ---------------------------------------------------------------------------
// Batched transpose: in [R,Cc] (f32 or bf16) -> out [Cc][ldout] bf16.
// Zero-fills dest rows r in [R, ldout) (grid.y must cover ldout rows).
// ---------------------------------------------------------------------------
template<bool IN_F32>
__global__ __launch_bounds__(256)
void transpose_kernel(const void* __restrict__ inp, short* __restrict__ outp,
                      int R, int Cc, int ldout)
{
    __shared__ short tile[64][65];
    const long in_off = (long)blockIdx.z * R * Cc;
    const long out_off = (long)blockIdx.z * Cc * ldout;
    const int bx = blockIdx.x << 6;  // input col base
    const int by = blockIdx.y << 6;  // input row base
    const int tx = threadIdx.x & 63, ty = threadIdx.x >> 6;
    #pragma unroll
    for (int i = ty; i < 64; i += 4) {
        const int r = by + i, c = bx + tx;
        short v = 0;
        if (r < R && c < Cc) {
            if constexpr (IN_F32) v = f2bf(((const float*)inp)[in_off + (long)r * Cc + c]);
            else                  v = ((const short*)inp)[in_off + (long)r * Cc + c];
        }
        tile[i][tx] = v;
    }
    __syncthreads();
    #pragma unroll
    for (int i = ty; i < 64; i += 4) {
        const int c = bx + i, r = by + tx;
        if (c < Cc && r < ldout) outp[out_off + (long)c * ldout + r] = tile[tx][i];
    }
}

// ---------------------------------------------------------------------------
__global__ __launch_bounds__(256)
void cast_kernel(const float* __restrict__ in, short* __restrict__ out)
{
    const long i = (long)blockIdx.x * 256 + threadIdx.x;
    const float4 v = ((const float4*)in)[i];
    short4b s; s[0] = f2bf(v.x); s[1] = f2bf(v.y); s[2] = f2bf(v.z); s[3] = f2bf(v.w);
    ((short4b*)out)[i] = s;
}

// ---------------------------------------------------------------------------
// LayerNorm over D=768, f32 in -> bf16 out. One 192-thread block per row.
// ---------------------------------------------------------------------------
__global__ __launch_bounds__(192)
void ln_kernel(const float* __restrict__ x, const float* __restrict__ g,
               const float* __restrict__ b, short* __restrict__ out)
{
    const long row = blockIdx.x;
    const float* xr = x + row * 768;
    const int t = threadIdx.x;
    const float4 v = *(const float4*)(xr + (t << 2));
    float s  = v.x + v.y + v.z + v.w;
    float sq = v.x * v.x + v.y * v.y + v.z * v.z + v.w * v.w;
    #pragma unroll
    for (int off = 32; off; off >>= 1) {
        s  += __shfl_xor(s, off);
        sq += __shfl_xor(sq, off);
    }
    __shared__ float ss[4], ssq[4];
    const int w = t >> 6;
    if ((t & 63) == 0) { ss[w] = s; ssq[w] = sq; }
    __syncthreads();
    s  = ss[0] + ss[1] + ss[2];
    sq = ssq[0] + ssq[1] + ssq[2];
    const float mean = s * (1.0f / 768.0f);
    const float var  = sq * (1.0f / 768.0f) - mean * mean;
    const float rstd = rsqrtf(var + 1e-5f);
    const float4 gv = *(const float4*)(g + (t << 2));
    const float4 bv = *(const float4*)(b + (t << 2));
    short4b o;
    o[0] = f2bf((v.x - mean) * rstd * gv.x + bv.x);
    o[1] = f2bf((v.y - mean) * rstd * gv.y + bv.y);
    o[2] = f2bf((v.z - mean) * rstd * gv.z + bv.z);
    o[3] = f2bf((v.w - mean) * rstd * gv.w + bv.w);
    *(short4b*)(out + row * 768 + (t << 2)) = o;
}

// ---------------------------------------------------------------------------
// Split-K reduce + bias + residual (+ optional LayerNorm).
// ---------------------------------------------------------------------------
template<bool DO_LN>
__global__ __launch_bounds__(192)
void reduce_kernel(const float* __restrict__ part, int nsplit, long pstride,
                   const float* __restrict__ resid, int rmod,
                   const float* __restrict__ bias,
                   const float* __restrict__ g, const float* __restrict__ bvec,
                   float* __restrict__ hout, short* __restrict__ hnout)
{
    const long row = blockIdx.x;
    const int t = threadIdx.x;
    const int c = t << 2;
    const float* rr = resid + (long)(row % rmod) * 768;
    float4 v = *(const float4*)(rr + c);
    const float4 bb = *(const float4*)(bias + c);
    v.x += bb.x; v.y += bb.y; v.z += bb.z; v.w += bb.w;
    for (int s = 0; s < nsplit; ++s) {
        const float4 p = *(const float4*)(part + (long)s * pstride + row * 768 + c);
        v.x += p.x; v.y += p.y; v.z += p.z; v.w += p.w;
    }
    *(float4*)(hout + row * 768 + c) = v;
    if constexpr (DO_LN) {
        float s  = v.x + v.y + v.z + v.w;
        float sq = v.x * v.x + v.y * v.y + v.z * v.z + v.w * v.w;
        #pragma unroll
        for (int off = 32; off; off >>= 1) {
            s  += __shfl_xor(s, off);
            sq += __shfl_xor(sq, off);
        }
        __shared__ float ss[4], ssq[4];
        const int wv = t >> 6;
        if ((t & 63) == 0) { ss[wv] = s; ssq[wv] = sq; }
        __syncthreads();
        s  = ss[0] + ss[1] + ss[2];
        sq = ssq[0] + ssq[1] + ssq[2];
        const float mean = s * (1.0f / 768.0f);
        const float var  = sq * (1.0f / 768.0f) - mean * mean;
        const float rstd = rsqrtf(var + 1e-5f);
        const float4 gv = *(const float4*)(g + c);
        const float4 bv = *(const float4*)(bvec + c);
        short4b o;
        o[0] = f2bf((v.x - mean) * rstd * gv.x + bv.x);
        o[1] = f2bf((v.y - mean) * rstd * gv.y + bv.y);
        o[2] = f2bf((v.z - mean) * rstd * gv.z + bv.z);
        o[3] = f2bf((v.w - mean) * rstd * gv.w + bv.w);
        *(short4b*)(hnout + row * 768 + c) = o;
    }
}

// ---------------------------------------------------------------------------
// GroupFC: out[b, g*10+f] = sum_d h[b,g,d]*dup_pool[g,d,f] + dup_bias.
// ---------------------------------------------------------------------------
__global__ __launch_bounds__(64)
void groupfc_kernel(const float* __restrict__ h, const float* __restrict__ dp,
                    const float* __restrict__ bias, float* __restrict__ out)
{
    const int bg = blockIdx.x;
    const int g = bg % 100;
    const int t = threadIdx.x;
    const float* hr = h + (long)bg * 768;
    const float* d = dp + (long)g * 7680;
    float acc[10];
    #pragma unroll
    for (int f = 0; f < 10; ++f) acc[f] = 0.0f;
    for (int k = t; k < 768; k += 64) {
        const float hv = hr[k];
        const float* dr = d + k * 10;
        #pragma unroll
        for (int f = 0; f < 10; ++f) acc[f] += hv * dr[f];
    }
    #pragma unroll
    for (int f = 0; f < 10; ++f) {
        #pragma unroll
        for (int off = 32; off; off >>= 1) acc[f] += __shfl_xor(acc[f], off);
    }
    if (t == 0) {
        const int b = bg / 100;
        #pragma unroll
        for (int f = 0; f < 10; ++f)
            out[(long)b * 1000 + g * 10 + f] = acc[f] + bias[g * 10 + f];
    }
}

// ---------------------------------------------------------------------------
extern "C" void kernel_launch(void* const* d_in, const int* in_sizes, int n_in,
                              void* d_out, int out_size, void* d_ws, size_t ws_size,
                              hipStream_t stream)
{
    const float* x       = (const float*)d_in[0];
    const float* W_embed = (const float*)d_in[1];
    const float* b_embed = (const float*)d_in[2];
    const float* qe      = (const float*)d_in[3];
    const float* ln1_g   = (const float*)d_in[4];
    const float* ln1_b   = (const float*)d_in[5];
    const float* Wq_s    = (const float*)d_in[6];
    const float* Wk_s    = (const float*)d_in[7];
    const float* Wv_s    = (const float*)d_in[8];
    const float* Wo_s    = (const float*)d_in[9];
    const float* bo_s    = (const float*)d_in[10];
    const float* ln2_g   = (const float*)d_in[11];
    const float* ln2_b   = (const float*)d_in[12];
    const float* Wq_c    = (const float*)d_in[13];
    const float* Wk_c    = (const float*)d_in[14];
    const float* Wv_c    = (const float*)d_in[15];
    const float* Wo_c    = (const float*)d_in[16];
    const float* bo_c    = (const float*)d_in[17];
    const float* ln3_g   = (const float*)d_in[18];
    const float* ln3_b   = (const float*)d_in[19];
    const float* W1      = (const float*)d_in[20];
    const float* b1      = (const float*)d_in[21];
    const float* W2      = (const float*)d_in[22];
    const float* b2      = (const float*)d_in[23];
    const float* dpool   = (const float*)d_in[24];
    const float* dbias   = (const float*)d_in[25];

    char* base = (char*)d_ws;
    size_t off = 0;
    auto alloc = [&](size_t bytes) -> void* {
        void* p = base + off;
        off += (bytes + 255) & ~(size_t)255;
        return p;
    };
    short* ek    = (short*)alloc(12544L * 768 * 2);      // emb bf16 [12544][768]
    short* ekT   = (short*)alloc(64L * 768 * 256 * 2);   // emb^T [b][768][256] zero-pad
    short* big   = (short*)alloc(6400L * 6144 * 2);      // xT, then ctx_c (compact)
    char*  shr   = (char*) alloc(4L * 6400 * 768 * 4);   // prep casts / partC
    float* h2    = (float*)alloc(6400L * 768 * 4);       // residual stream (b-dep)
    short* hn3   = (short*)alloc(6400L * 768 * 2);
    short* t1    = (short*)alloc(6400L * 2048 * 2);
    short* WembT = (short*)alloc(768L * 2048 * 2);
    short* W1T   = (short*)alloc(2048L * 768 * 2);
    short* W2T   = (short*)alloc(768L * 2048 * 2);
    short* WqkTc = (short*)alloc(6144L * 768 * 2);       // [h][768][768] planes
    short* WvoTc = (short*)alloc(768L * 6144 * 2);
    short* WqsT  = (short*)alloc(6144L * 768 * 2);
    short* WksT  = (short*)alloc(6144L * 768 * 2);
    short* WvsT  = (short*)alloc(6144L * 768 * 2);
    short* WosT  = (short*)alloc(768L * 6144 * 2);
    short* hn1   = (short*)alloc(128L * 768 * 2);        // pad rows stale (finite)
    short* q_s   = (short*)alloc(128L * 6144 * 2);
    short* k_s   = (short*)alloc(128L * 6144 * 2);
    short* v_s   = (short*)alloc(128L * 6144 * 2);
    short* ctx_s = (short*)alloc(128L * 6144 * 2);
    short* v_sT  = (short*)alloc(6144L * 128 * 2);       // zero-pad cols >= 100
    short* qt_c  = (short*)alloc(128L * 6144 * 2);
    float* partS = (float*)alloc(8L * 100 * 768 * 4);
    float* h1    = (float*)alloc(128L * 768 * 4);
    short* hn2   = (short*)alloc(128L * 768 * 2);
    (void)ws_size; (void)in_sizes; (void)n_in; (void)out_size;

    // shared-region aliases (phase-disjoint)
    short* CQ    = (short*)shr;                          // prep casts
    short* CK    = CQ + 4718592L;
    short* CV    = CK + 4718592L;
    short* WoTc  = CV + 4718592L;
    float* partC = (float*)shr;                          // [4][6400][768] f32

    const float scale = 0.03608439182435161f;  // 768^-0.5

    // ================= weight prep =================
    transpose_kernel<true><<<dim3(12, 32, 1), 256, 0, stream>>>(W_embed, WembT, 2048, 768, 2048);
    transpose_kernel<true><<<dim3(32, 12, 1), 256, 0, stream>>>(W1, W1T, 768, 2048, 768);
    transpose_kernel<true><<<dim3(12, 32, 1), 256, 0, stream>>>(W2, W2T, 2048, 768, 2048);
    transpose_kernel<true><<<dim3(96, 12, 1), 256, 0, stream>>>(Wq_s, WqsT, 768, 6144, 768);
    transpose_kernel<true><<<dim3(96, 12, 1), 256, 0, stream>>>(Wk_s, WksT, 768, 6144, 768);
    transpose_kernel<true><<<dim3(96, 12, 1), 256, 0, stream>>>(Wv_s, WvsT, 768, 6144, 768);
    transpose_kernel<true><<<dim3(12, 96, 1), 256, 0, stream>>>(Wo_s, WosT, 6144, 768, 6144);

    cast_kernel<<<dim3(4608), 256, 0, stream>>>(Wq_c, CQ);
    cast_kernel<<<dim3(4608), 256, 0, stream>>>(Wk_c, CK);
    // WqkTc[h][e][d] = sum_f Wq_c[d, h*768+f] * Wk_c[e, h*768+f]
    gemm_kernel<0, true><<<dim3(6, 6, 8), 256, 0, stream>>>(
        CK, CQ, nullptr, nullptr, WqkTc,
        768, 768, 768, 768, 768, 6144, 6144, 768, 8,
        0L, 768L, 0L, 768L, 0L, 589824L, 1.0f);
    cast_kernel<<<dim3(4608), 256, 0, stream>>>(Wv_c, CV);
    transpose_kernel<true><<<dim3(12, 96, 1), 256, 0, stream>>>(Wo_c, WoTc, 6144, 768, 6144);
    // WvoTc[d][h*768+e] = sum_f WoTc[d, h*768+f] * Wv_c[e, h*768+f]
    gemm_kernel<0, true><<<dim3(6, 6, 8), 256, 0, stream>>>(
        WoTc, CV, nullptr, nullptr, WvoTc,
        768, 768, 768, 768, 768, 6144, 6144, 6144, 8,
        0L, 768L, 0L, 768L, 0L, 768L, 1.0f);

    // ================= embed =================
    short* xT = big;  // [12544][2048] bf16
    transpose_kernel<true><<<dim3(4, 32, 64), 256, 0, stream>>>(x, xT, 2048, 196, 2048);
    gemm_kernel<1, true><<<dim3(6, 98, 1), 256, 0, stream>>>(
        xT, WembT, b_embed, nullptr, ek,
        12544, 768, 2048, 12544, 768, 2048, 2048, 768, 1,
        0L, 0L, 0L, 0L, 0L, 0L, 1.0f);
    transpose_kernel<false><<<dim3(12, 4, 64), 256, 0, stream>>>(ek, ekT, 196, 768, 256);

    // ================= self-attention (batch-invariant, 100 rows) ==========
    ln_kernel<<<dim3(100), 192, 0, stream>>>(qe, ln1_g, ln1_b, hn1);
    gemm_kernel<0, true><<<dim3(48, 1, 1), 256, 0, stream>>>(
        hn1, WqsT, nullptr, nullptr, q_s,
        100, 6144, 768, 128, 6144, 768, 768, 6144, 1, 0,0,0,0,0,0, 1.0f);
    gemm_kernel<0, true><<<dim3(48, 1, 1), 256, 0, stream>>>(
        hn1, WksT, nullptr, nullptr, k_s,
        100, 6144, 768, 128, 6144, 768, 768, 6144, 1, 0,0,0,0,0,0, 1.0f);
    gemm_kernel<0, true><<<dim3(48, 1, 1), 256, 0, stream>>>(
        hn1, WvsT, nullptr, nullptr, v_s,
        100, 6144, 768, 128, 6144, 768, 768, 6144, 1, 0,0,0,0,0,0, 1.0f);
    transpose_kernel<false><<<dim3(96, 2, 1), 256, 0, stream>>>(v_s, v_sT, 100, 6144, 128);
    // fused: scores + softmax + PV  -> ctx_s[q][h*768+e]
    attn_kernel<8><<<dim3(8), 256, 0, stream>>>(
        q_s, k_s, v_sT, ctx_s,
        100, 8, 6144, 6144, 128, 6144,
        768, 768, 0L, 0L, 0L, scale);
    // o_s partial (split-K=8 over INNER): partS[s][q][n]
    gemm_kernel<0, false><<<dim3(6, 1, 8), 256, 0, stream>>>(
        ctx_s, WosT, nullptr, nullptr, partS,
        100, 768, 768, 128, 768, 6144, 6144, 768, 8,
        0L, 768L, 0L, 768L, 0L, 76800L, 1.0f);
    // h1 = qe + o_s + bo_s;  hn2 = LN2(h1)
    reduce_kernel<true><<<dim3(100), 192, 0, stream>>>(
        partS, 8, 76800L, qe, 100, bo_s, ln2_g, ln2_b, h1, hn2);

    // ================= cross-attention =================
    gemm_kernel<0, true><<<dim3(48, 1, 1), 256, 0, stream>>>(
        hn2, WqkTc, nullptr, nullptr, qt_c,
        100, 6144, 768, 128, 6144, 768, 768, 6144, 1, 0,0,0,0,0,0, 1.0f);
    // fused: scores + softmax + PV -> big[b*100+q][h*768+e]
    attn_kernel<14><<<dim3(512), 256, 0, stream>>>(
        qt_c, ek, ekT, big,
        196, 8, 6144, 768, 256, 6144,
        0, 0, 150528L, 196608L, 614400L, scale);
    // o_c partial (split-K=4, Kc=1536): partC[s][6400][768]
    gemm_kernel<0, false><<<dim3(6, 50, 4), 256, 0, stream>>>(
        big, WvoTc, nullptr, nullptr, partC,
        6400, 768, 1536, 6400, 768, 6144, 6144, 768, 4,
        0L, 1536L, 0L, 1536L, 0L, 4915200L, 1.0f);
    // h2 = h1[q] + o_c + bo_c;  hn3 = LN3(h2)
    reduce_kernel<true><<<dim3(6400), 192, 0, stream>>>(
        partC, 4, 4915200L, h1, 100, bo_c, ln3_g, ln3_b, h2, hn3);

    // ================= MLP =================
    gemm_kernel<2, true><<<dim3(16, 50, 1), 256, 0, stream>>>(
        hn3, W1T, b1, nullptr, t1,
        6400, 2048, 768, 6400, 2048, 768, 768, 2048, 1, 0,0,0,0,0,0, 1.0f);
    // W2 partial (split-K=4, Kc=512)
    gemm_kernel<0, false><<<dim3(6, 50, 4), 256, 0, stream>>>(
        t1, W2T, nullptr, nullptr, partC,
        6400, 768, 512, 6400, 768, 2048, 2048, 768, 4,
        0L, 512L, 0L, 512L, 0L, 4915200L, 1.0f);
    // h2 += sum + b2  (in-place, no LN)
    reduce_kernel<false><<<dim3(6400), 192, 0, stream>>>(
        partC, 4, 4915200L, h2, 6400, b2, nullptr, nullptr, h2, nullptr);

    // ================= GroupFC =================
    groupfc_kernel<<<dim3(6400), 64, 0, stream>>>(h2, dpool, dbias, (float*)d_out);
}